// Round 3
// baseline (123.567 us; speedup 1.0000x reference)
//
#include <hip/hip_runtime.h>
#include <hip/hip_bf16.h>

// InfoNCE loss, N=8192 D=512 C=128.
// Fixed-shift softmax (M=10): t_ij = s_ij/tau - 10 in [-20, 0].
//   Z_i  = sum_{class!=} e^{t_ij}
//   term = -t_p + log(Z + e^{t_p}) ~= -t_p + logZ + e^{t_p}/Z   (next term <=1e-6)
// Per-row linear partials (Z, NS=sum t_p, P1=sum e^{t_p}) accumulated in the
// GEMM epilogue; CNT recovered exactly from an integer class histogram.
// Symmetric: tiles bj>=bi only; off-diag tiles emit row-side AND col-side
// partials into deterministic slots (slot = other block index).
// K2 is a 2-phase double-buffered pipeline (T3 minimum recipe) with
// global_load_lds(16B) staging, XOR-swizzled LDS (0 bank conflicts), and
// XCD-bijective chunked block swizzle for A-panel L2 residency.

constexpr int   D      = 512;
constexpr int   BT     = 128;        // tile dim
constexpr int   BK     = 64;
constexpr int   NSTEP  = D / BK;     // 8
constexpr float TAUINV = 10.0f;
constexpr float SHIFT  = 10.0f;

typedef __attribute__((ext_vector_type(8))) short bf16x8;
typedef __attribute__((ext_vector_type(4))) float f32x4;

__device__ inline ushort f2bf(float x) {
    unsigned u = __builtin_bit_cast(unsigned, x);
    unsigned r = (u + 0x7fffu + ((u >> 16) & 1u)) >> 16;   // RNE
    return (ushort)r;
}

__device__ inline void gload_lds16(const ushort* g, ushort* l) {
    __builtin_amdgcn_global_load_lds(
        (const __attribute__((address_space(1))) void*)g,
        (__attribute__((address_space(3))) void*)l, 16, 0, 0);
}

// ---------------- K1: L2-normalize rows, f32 -> bf16 (+ class histogram) ----
__global__ void k_normalize(const float* __restrict__ emb,
                            const int* __restrict__ classes,
                            ushort* __restrict__ normed,
                            int* __restrict__ hist, int n) {
    int row  = blockIdx.x * 4 + (threadIdx.x >> 6);
    int lane = threadIdx.x & 63;
    if (row >= n) return;
    if (lane == 0) atomicAdd(&hist[classes[row] & 1023], 1);
    const float4* src = (const float4*)(emb + (size_t)row * D);
    float4 a = src[lane * 2];
    float4 b = src[lane * 2 + 1];
    float ss = a.x*a.x + a.y*a.y + a.z*a.z + a.w*a.w
             + b.x*b.x + b.y*b.y + b.z*b.z + b.w*b.w;
#pragma unroll
    for (int m = 1; m < 64; m <<= 1) ss += __shfl_xor(ss, m, 64);
    float sc = 1.0f / fmaxf(sqrtf(ss), 1e-12f);
    uint4 o;
    o.x = (unsigned)f2bf(a.x * sc) | ((unsigned)f2bf(a.y * sc) << 16);
    o.y = (unsigned)f2bf(a.z * sc) | ((unsigned)f2bf(a.w * sc) << 16);
    o.z = (unsigned)f2bf(b.x * sc) | ((unsigned)f2bf(b.y * sc) << 16);
    o.w = (unsigned)f2bf(b.z * sc) | ((unsigned)f2bf(b.w * sc) << 16);
    *(uint4*)&normed[(size_t)row * D + lane * 8] = o;
}

// ---------------- K2: symmetric masked-exp GEMM, 2-phase pipeline ----------
// Zpart layout: plane q in 0..2 (Z,NS,P1), each [64 slots][n rows].
__global__ __launch_bounds__(256) void k_zgemm(
    const ushort* __restrict__ normed, const int* __restrict__ classes,
    float* __restrict__ Zpart, int n, int nb, int npairs) {
    __shared__ ushort lds[2][2][BT * BK];     // [buf][A/B][8192] = 64 KB
    __shared__ int clsrow[BT], clscol[BT];

    const int tid  = threadIdx.x;
    const int lane = tid & 63;
    const int w    = tid >> 6;
    const int wm   = w >> 1, wn = w & 1;
    const int l15  = lane & 15, l4 = lane >> 4;
    const size_t QS = (size_t)64 * n;

    // XCD-bijective chunked swizzle (m204): consecutive orig ids per XCD.
    int q8 = npairs >> 3, r8 = npairs & 7;
    int xcd = blockIdx.x & 7, off = blockIdx.x >> 3;
    int orig = (xcd < r8 ? xcd * (q8 + 1) : r8 * (q8 + 1) + (xcd - r8) * q8) + off;

    // orig -> (bi, bj), bj >= bi (triangular walk, bi-major)
    int idx = orig, bi = 0, rem = nb;
    while (idx >= rem) { idx -= rem; ++bi; --rem; }
    const int bj = bi + idx;
    const int row0 = bi * BT, c0 = bj * BT;
    const bool diagblk = (bi == bj);

    if (tid < BT) clsrow[tid] = classes[row0 + tid];
    else          clscol[tid - BT] = classes[c0 + tid - BT];

    // precompute staging addresses (inverse-swizzled global source, rule #21)
    const int srow = lane >> 3;   // 0..7: row within 8-row chunk
    const int scs  = lane & 7;    // 16B slot within 128B row
    size_t gA[4], gB[4]; int ldst[4];
#pragma unroll
    for (int it = 0; it < 4; ++it) {
        int chunk = it * 4 + w;                // wave-uniform chunk id 0..15
        int row   = chunk * 8 + srow;          // 0..127
        int cg    = scs ^ (row & 7);           // swizzled source 16B-slot
        gA[it]    = (size_t)(row0 + row) * D + cg * 8;
        gB[it]    = (size_t)(c0   + row) * D + cg * 8;
        ldst[it]  = chunk * 512;               // shorts; lane*16B implicit
    }

    auto STAGE = [&](int buf, int kk) {
#pragma unroll
        for (int it = 0; it < 4; ++it) {
            gload_lds16(normed + gA[it] + kk, &lds[buf][0][ldst[it]]);
            gload_lds16(normed + gB[it] + kk, &lds[buf][1][ldst[it]]);
        }
    };

    f32x4 acc[4][4];
#pragma unroll
    for (int a = 0; a < 4; ++a)
#pragma unroll
        for (int b = 0; b < 4; ++b) acc[a][b] = (f32x4){0.f, 0.f, 0.f, 0.f};

    STAGE(0, 0);
    __syncthreads();                            // drain prologue loads

    for (int kt = 0; kt < NSTEP; ++kt) {
        const int cur = kt & 1;
        if (kt + 1 < NSTEP) STAGE(cur ^ 1, (kt + 1) * BK);   // prefetch next
        const char* la = (const char*)&lds[cur][0][0];
        const char* lb = (const char*)&lds[cur][1][0];
#pragma unroll
        for (int ks = 0; ks < 2; ++ks) {
            bf16x8 af[4], bfr[4];
#pragma unroll
            for (int mf = 0; mf < 4; ++mf) {
                int ra = wm * 64 + mf * 16 + l15;
                af[mf] = *(const bf16x8*)(la + ra * 128 + (((ks * 4 + l4) ^ (ra & 7)) << 4));
            }
#pragma unroll
            for (int nf = 0; nf < 4; ++nf) {
                int rb = wn * 64 + nf * 16 + l15;
                bfr[nf] = *(const bf16x8*)(lb + rb * 128 + (((ks * 4 + l4) ^ (rb & 7)) << 4));
            }
#pragma unroll
            for (int mf = 0; mf < 4; ++mf)
#pragma unroll
                for (int nf = 0; nf < 4; ++nf)
                    acc[mf][nf] = __builtin_amdgcn_mfma_f32_16x16x32_bf16(
                        af[mf], bfr[nf], acc[mf][nf], 0, 0, 0);
        }
        __syncthreads();     // drains vmcnt(0): prefetched buffer ready
    }

    // ---- epilogue: masked accumulation of (Z, NS, P1) ----
    float cqz[4] = {0,0,0,0}, cqn[4] = {0,0,0,0}, cqp[4] = {0,0,0,0};
    float* redr = (float*)&lds[0][0][0];      // [2(wn)][128][3]
    float* redc = (float*)&lds[0][1][0];      // [2(wm)][128][3]

#pragma unroll
    for (int mf = 0; mf < 4; ++mf) {
#pragma unroll
        for (int r = 0; r < 4; ++r) {
            int rr = wm * 64 + mf * 16 + l4 * 4 + r;
            int rg = row0 + rr;
            int cr = clsrow[rr];
            float z = 0.f, ns = 0.f, p1 = 0.f;
#pragma unroll
            for (int nf = 0; nf < 4; ++nf) {
                int cc = wn * 64 + nf * 16 + l15;
                float t = fmaf(acc[mf][nf][r], TAUINV, -SHIFT);
                float e = __expf(t);
                bool same = (cr == clscol[cc]);
                bool dg   = (rg == c0 + cc);
                if (!same) {
                    z += e; cqz[nf] += e;
                } else if (!dg) {
                    ns += t; p1 += e; cqn[nf] += t; cqp[nf] += e;
                }
            }
#pragma unroll
            for (int m = 1; m < 16; m <<= 1) {
                z  += __shfl_xor(z,  m, 16);
                ns += __shfl_xor(ns, m, 16);
                p1 += __shfl_xor(p1, m, 16);
            }
            if (l15 == 0) {
                float* p = &redr[(wn * 128 + rr) * 3];
                p[0] = z; p[1] = ns; p[2] = p1;
            }
        }
    }
    if (!diagblk) {
#pragma unroll
        for (int nf = 0; nf < 4; ++nf) {
            float z = cqz[nf], nsv = cqn[nf], p = cqp[nf];
            z += __shfl_xor(z, 16, 64);  z += __shfl_xor(z, 32, 64);
            nsv += __shfl_xor(nsv, 16, 64); nsv += __shfl_xor(nsv, 32, 64);
            p += __shfl_xor(p, 16, 64);  p += __shfl_xor(p, 32, 64);
            if (l4 == 0) {
                float* pp = &redc[(wm * 128 + wn * 64 + nf * 16 + l15) * 3];
                pp[0] = z; pp[1] = nsv; pp[2] = p;
            }
        }
    }
    __syncthreads();

    if (tid < BT) {                           // row-side partials, slot = bj
#pragma unroll
        for (int q = 0; q < 3; ++q)
            Zpart[q * QS + (size_t)bj * n + row0 + tid] =
                redr[(0 * 128 + tid) * 3 + q] + redr[(1 * 128 + tid) * 3 + q];
    } else if (!diagblk) {                    // col-side partials, slot = bi
        int cc = tid - BT;
#pragma unroll
        for (int q = 0; q < 3; ++q)
            Zpart[q * QS + (size_t)bi * n + c0 + cc] =
                redc[(0 * 128 + cc) * 3 + q] + redc[(1 * 128 + cc) * 3 + q];
    }
}

// ---------------- K3: per-row closed-form terms ----------------
__global__ void k_rowterms(const float* __restrict__ Zpart,
                           const int* __restrict__ classes,
                           const int* __restrict__ hist,
                           float* __restrict__ rowloss,
                           float* __restrict__ rowcnt, int n) {
    int i = blockIdx.x * 256 + threadIdx.x;
    if (i >= n) return;
    const size_t QS = (size_t)64 * n;
    float z = 0.f, ns = 0.f, p1 = 0.f;
    for (int s = 0; s < 64; ++s) {
        size_t o = (size_t)s * n + i;
        z  += Zpart[o];
        ns += Zpart[QS + o];
        p1 += Zpart[2 * QS + o];
    }
    float c = (float)(hist[classes[i] & 1023] - 1);
    rowloss[i] = -ns + c * logf(z) + p1 / z;
    rowcnt[i]  = c;
}

// ---------------- K4: final deterministic reduction ----------------
__global__ void k_final(const float* __restrict__ rowloss,
                        const float* __restrict__ rowcnt,
                        float* __restrict__ out, int n) {
    __shared__ float sl[1024];
    __shared__ float sc[1024];
    float l = 0.f, c = 0.f;
    for (int i = threadIdx.x; i < n; i += 1024) {
        l += rowloss[i];
        c += rowcnt[i];
    }
    sl[threadIdx.x] = l;
    sc[threadIdx.x] = c;
    __syncthreads();
    for (int s = 512; s > 0; s >>= 1) {
        if (threadIdx.x < s) {
            sl[threadIdx.x] += sl[threadIdx.x + s];
            sc[threadIdx.x] += sc[threadIdx.x + s];
        }
        __syncthreads();
    }
    if (threadIdx.x == 0)
        out[0] = (sc[0] > 0.f) ? sl[0] / sc[0] : 0.f;
}

extern "C" void kernel_launch(void* const* d_in, const int* in_sizes, int n_in,
                              void* d_out, int out_size, void* d_ws, size_t ws_size,
                              hipStream_t stream) {
    const float* emb     = (const float*)d_in[0];
    const int*   classes = (const int*)d_in[1];
    float*       out     = (float*)d_out;
    const int n  = in_sizes[1];               // 8192
    const int nb = n / BT;                    // 64
    const int npairs = nb * (nb + 1) / 2;     // 2080

    ushort* normed  = (ushort*)d_ws;                                   // 8 MB
    float*  Zpart   = (float*)((char*)d_ws + (size_t)n * D * 2);       // 3*64*n*4 = 6 MB
    float*  rowloss = Zpart + (size_t)3 * 64 * n;
    float*  rowcnt  = rowloss + n;
    int*    hist    = (int*)(rowcnt + n);                              // 4 KB

    hipMemsetAsync(hist, 0, 1024 * sizeof(int), stream);
    k_normalize<<<n / 4, 256, 0, stream>>>(emb, classes, normed, hist, n);
    k_zgemm<<<npairs, 256, 0, stream>>>(normed, classes, Zpart, n, nb, npairs);
    k_rowterms<<<(n + 255) / 256, 256, 0, stream>>>(Zpart, classes, hist, rowloss, rowcnt, n);
    k_final<<<1, 1024, 0, stream>>>(rowloss, rowcnt, out, n);
}

// Round 4
// 94.037 us; speedup vs baseline: 1.3140x; 1.3140x over previous
//
#include <hip/hip_runtime.h>
#include <hip/hip_bf16.h>

// InfoNCE loss, N=8192 D=512 C=128.
// Fixed-shift softmax (M=10): t_ij = s_ij/tau - 10 in [-20, 0].
//   Z_i  = sum_{class!=} e^{t_ij}
//   term = -t_p + log(Z + e^{t_p}) ~= -t_p + logZ + e^{t_p}/Z   (next term <=1e-6)
// Per-row linear partials (Z, NS=sum t_p, P1=sum e^{t_p}) accumulated in the
// GEMM epilogue; CNT from a separate LDS-histogram kernel (no global atomics).
// Symmetric: tiles bj>=bi only, enumerated in 8x8 super-tiles for 2D L2
// locality + XCD-chunked swizzle. K2 pipeline: BK=32, 3 LDS buffers,
// raw s_barrier + counted vmcnt(4) (T4 - loads stay in flight across
// barriers), XOR-swizzled LDS (conflict-free), global_load_lds(16B).

constexpr int   D      = 512;
constexpr int   BT     = 128;        // tile dim
constexpr int   BK     = 32;
constexpr int   NSTEP  = D / BK;     // 16
constexpr float TAUINV = 10.0f;
constexpr float SHIFT  = 10.0f;

typedef __attribute__((ext_vector_type(8))) short bf16x8;
typedef __attribute__((ext_vector_type(4))) float f32x4;

__device__ inline ushort f2bf(float x) {
    unsigned u = __builtin_bit_cast(unsigned, x);
    unsigned r = (u + 0x7fffu + ((u >> 16) & 1u)) >> 16;   // RNE
    return (ushort)r;
}

__device__ inline void gload_lds16(const ushort* g, ushort* l) {
    __builtin_amdgcn_global_load_lds(
        (const __attribute__((address_space(1))) void*)g,
        (__attribute__((address_space(3))) void*)l, 16, 0, 0);
}

// ---------------- K0: class histogram (LDS, single block) ----------------
__global__ void k_hist(const int* __restrict__ classes, int* __restrict__ hist, int n) {
    __shared__ int h[1024];
    h[threadIdx.x] = 0;
    __syncthreads();
    for (int i = threadIdx.x; i < n; i += 1024)
        atomicAdd(&h[classes[i] & 1023], 1);
    __syncthreads();
    hist[threadIdx.x] = h[threadIdx.x];
}

// ---------------- K1: L2-normalize rows, f32 -> bf16 ----------------
__global__ void k_normalize(const float* __restrict__ emb,
                            ushort* __restrict__ normed, int n) {
    int row  = blockIdx.x * 4 + (threadIdx.x >> 6);
    int lane = threadIdx.x & 63;
    if (row >= n) return;
    const float4* src = (const float4*)(emb + (size_t)row * D);
    float4 a = src[lane * 2];
    float4 b = src[lane * 2 + 1];
    float ss = a.x*a.x + a.y*a.y + a.z*a.z + a.w*a.w
             + b.x*b.x + b.y*b.y + b.z*b.z + b.w*b.w;
#pragma unroll
    for (int m = 1; m < 64; m <<= 1) ss += __shfl_xor(ss, m, 64);
    float sc = 1.0f / fmaxf(sqrtf(ss), 1e-12f);
    uint4 o;
    o.x = (unsigned)f2bf(a.x * sc) | ((unsigned)f2bf(a.y * sc) << 16);
    o.y = (unsigned)f2bf(a.z * sc) | ((unsigned)f2bf(a.w * sc) << 16);
    o.z = (unsigned)f2bf(b.x * sc) | ((unsigned)f2bf(b.y * sc) << 16);
    o.w = (unsigned)f2bf(b.z * sc) | ((unsigned)f2bf(b.w * sc) << 16);
    *(uint4*)&normed[(size_t)row * D + lane * 8] = o;
}

// ---------------- K2: symmetric masked-exp GEMM, 3-deep pipeline -----------
// Zpart: plane q in 0..2 (Z,NS,P1), each [64 slots][n rows].
__global__ __launch_bounds__(256, 3) void k_zgemm(
    const ushort* __restrict__ normed, const int* __restrict__ classes,
    float* __restrict__ Zpart, int n, int nb, int npairs) {
    __shared__ ushort lds[3][2][BT * BK];     // 3 bufs x (A,B) x 8KB = 48 KB
    __shared__ int clsrow[BT], clscol[BT];

    const int tid  = threadIdx.x;
    const int lane = tid & 63;
    const int w    = tid >> 6;
    const int wm   = w >> 1, wn = w & 1;
    const int l15  = lane & 15, l4 = lane >> 4;
    const size_t QS = (size_t)64 * n;

    // XCD-chunked swizzle (bijective: npairs=2080, 2080%8==0 handled generally)
    int q8 = npairs >> 3, r8 = npairs & 7;
    int xcd = blockIdx.x & 7, off = blockIdx.x >> 3;
    int orig = (xcd < r8 ? xcd * (q8 + 1) : r8 * (q8 + 1) + (xcd - r8) * q8) + off;

    // orig -> (bi,bj) via 8x8 super-tile walk (2D locality within an XCD)
    const int sgrid = nb >> 3;               // 8
    int idx = orig, si = 0;
    for (;;) {
        int rowcnt = 36 + (sgrid - 1 - si) * 64;
        if (idx < rowcnt) break;
        idx -= rowcnt; ++si;
    }
    int bi, bj;
    if (idx < 36) {                          // diagonal super-tile (bj>=bi)
        int u = 0, rem = 8;
        while (idx >= rem) { idx -= rem; ++u; --rem; }
        bi = si * 8 + u; bj = si * 8 + u + idx;
    } else {
        idx -= 36;
        int sj = si + 1 + (idx >> 6);
        int v  = idx & 63;
        bi = si * 8 + (v >> 3); bj = sj * 8 + (v & 7);
    }
    const int row0 = bi * BT, c0 = bj * BT;
    const bool diagblk = (bi == bj);

    if (tid < BT) clsrow[tid] = classes[row0 + tid];
    else          clscol[tid - BT] = classes[c0 + tid - BT];

    // staging addresses: chunk = 16 rows x 64B (1KB). wave w owns chunks
    // {2w, 2w+1} of A and of B. lane l: row = c*16 + (l>>2), lds slot = l&3,
    // source slot cg = (l&3) ^ (row&3)  (rule #21: inverse-swizzled source).
    const int lrow = lane >> 2;              // 0..15
    const int cg   = (lane & 3) ^ (lrow & 3);
    size_t ga[2], gb[2]; int lo[2];
#pragma unroll
    for (int it = 0; it < 2; ++it) {
        int chunk = w * 2 + it;              // 0..7
        int row   = chunk * 16 + lrow;
        ga[it] = (size_t)(row0 + row) * D + cg * 8;
        gb[it] = (size_t)(c0   + row) * D + cg * 8;
        lo[it] = chunk * 512;                // shorts
    }

    auto STAGE = [&](int buf, int kk) {
#pragma unroll
        for (int it = 0; it < 2; ++it) {
            gload_lds16(normed + ga[it] + kk, &lds[buf][0][lo[it]]);
            gload_lds16(normed + gb[it] + kk, &lds[buf][1][lo[it]]);
        }
    };

    f32x4 acc[4][4];
#pragma unroll
    for (int a = 0; a < 4; ++a)
#pragma unroll
        for (int b = 0; b < 4; ++b) acc[a][b] = (f32x4){0.f, 0.f, 0.f, 0.f};

    // prologue: 2 buffers in flight, wait only for the first (vmcnt counts
    // this wave's outstanding gload_lds: 8 issued, 4 newest may remain)
    STAGE(0, 0);
    STAGE(1, BK);
    __builtin_amdgcn_sched_barrier(0);
    asm volatile("s_waitcnt vmcnt(4)" ::: "memory");
    __builtin_amdgcn_s_barrier();
    __builtin_amdgcn_sched_barrier(0);

#pragma unroll
    for (int kt = 0; kt < NSTEP; ++kt) {
        const int b = kt % 3;
        if (kt + 2 < NSTEP) STAGE((kt + 2) % 3, (kt + 2) * BK);
        const char* la = (const char*)&lds[b][0][0];
        const char* lb = (const char*)&lds[b][1][0];
        bf16x8 af[4], bfr[4];
#pragma unroll
        for (int mf = 0; mf < 4; ++mf) {
            int ra = wm * 64 + mf * 16 + l15;
            af[mf] = *(const bf16x8*)(la + ra * 64 + (((l4 ^ (ra & 3))) << 4));
        }
#pragma unroll
        for (int nf = 0; nf < 4; ++nf) {
            int rb = wn * 64 + nf * 16 + l15;
            bfr[nf] = *(const bf16x8*)(lb + rb * 64 + (((l4 ^ (rb & 3))) << 4));
        }
#pragma unroll
        for (int mf = 0; mf < 4; ++mf)
#pragma unroll
            for (int nf = 0; nf < 4; ++nf)
                acc[mf][nf] = __builtin_amdgcn_mfma_f32_16x16x32_bf16(
                    af[mf], bfr[nf], acc[mf][nf], 0, 0, 0);
        __builtin_amdgcn_sched_barrier(0);
        if (kt + 2 < NSTEP)       asm volatile("s_waitcnt vmcnt(4)" ::: "memory");
        else if (kt + 2 == NSTEP) asm volatile("s_waitcnt vmcnt(0)" ::: "memory");
        if (kt + 1 < NSTEP) {
            __builtin_amdgcn_s_barrier();
            __builtin_amdgcn_sched_barrier(0);
        }
    }
    __syncthreads();   // full drain before LDS overlay

    // ---- epilogue: masked accumulation of (Z, NS, P1) ----
    float cqz[4] = {0,0,0,0}, cqn[4] = {0,0,0,0}, cqp[4] = {0,0,0,0};
    float* redr = (float*)&lds[0][0][0];      // [2(wn)][128][3]
    float* redc = (float*)&lds[1][0][0];      // [2(wm)][128][3]

#pragma unroll
    for (int mf = 0; mf < 4; ++mf) {
#pragma unroll
        for (int r = 0; r < 4; ++r) {
            int rr = wm * 64 + mf * 16 + l4 * 4 + r;
            int rg = row0 + rr;
            int cr = clsrow[rr];
            float z = 0.f, ns = 0.f, p1 = 0.f;
#pragma unroll
            for (int nf = 0; nf < 4; ++nf) {
                int cc = wn * 64 + nf * 16 + l15;
                float t = fmaf(acc[mf][nf][r], TAUINV, -SHIFT);
                float e = __expf(t);
                bool same = (cr == clscol[cc]);
                bool dg   = (rg == c0 + cc);
                if (!same) {
                    z += e; cqz[nf] += e;
                } else if (!dg) {
                    ns += t; p1 += e; cqn[nf] += t; cqp[nf] += e;
                }
            }
#pragma unroll
            for (int m = 1; m < 16; m <<= 1) {
                z  += __shfl_xor(z,  m, 16);
                ns += __shfl_xor(ns, m, 16);
                p1 += __shfl_xor(p1, m, 16);
            }
            if (l15 == 0) {
                float* p = &redr[(wn * 128 + rr) * 3];
                p[0] = z; p[1] = ns; p[2] = p1;
            }
        }
    }
    if (!diagblk) {
#pragma unroll
        for (int nf = 0; nf < 4; ++nf) {
            float z = cqz[nf], nsv = cqn[nf], p = cqp[nf];
            z += __shfl_xor(z, 16, 64);  z += __shfl_xor(z, 32, 64);
            nsv += __shfl_xor(nsv, 16, 64); nsv += __shfl_xor(nsv, 32, 64);
            p += __shfl_xor(p, 16, 64);  p += __shfl_xor(p, 32, 64);
            if (l4 == 0) {
                float* pp = &redc[(wm * 128 + wn * 64 + nf * 16 + l15) * 3];
                pp[0] = z; pp[1] = nsv; pp[2] = p;
            }
        }
    }
    __syncthreads();

    if (tid < BT) {                           // row-side partials, slot = bj
#pragma unroll
        for (int q = 0; q < 3; ++q)
            Zpart[q * QS + (size_t)bj * n + row0 + tid] =
                redr[(0 * 128 + tid) * 3 + q] + redr[(1 * 128 + tid) * 3 + q];
    } else if (!diagblk) {                    // col-side partials, slot = bi
        int cc = tid - BT;
#pragma unroll
        for (int q = 0; q < 3; ++q)
            Zpart[q * QS + (size_t)bi * n + c0 + cc] =
                redc[(0 * 128 + cc) * 3 + q] + redc[(1 * 128 + cc) * 3 + q];
    }
}

// ---------------- K3: per-row closed-form terms ----------------
__global__ void k_rowterms(const float* __restrict__ Zpart,
                           const int* __restrict__ classes,
                           const int* __restrict__ hist,
                           float* __restrict__ rowloss,
                           float* __restrict__ rowcnt, int n) {
    int i = blockIdx.x * 256 + threadIdx.x;
    if (i >= n) return;
    const size_t QS = (size_t)64 * n;
    float z = 0.f, ns = 0.f, p1 = 0.f;
    for (int s = 0; s < 64; ++s) {
        size_t o = (size_t)s * n + i;
        z  += Zpart[o];
        ns += Zpart[QS + o];
        p1 += Zpart[2 * QS + o];
    }
    float c = (float)(hist[classes[i] & 1023] - 1);
    rowloss[i] = -ns + c * logf(z) + p1 / z;
    rowcnt[i]  = c;
}

// ---------------- K4: final deterministic reduction ----------------
__global__ void k_final(const float* __restrict__ rowloss,
                        const float* __restrict__ rowcnt,
                        float* __restrict__ out, int n) {
    __shared__ float sl[1024];
    __shared__ float sc[1024];
    float l = 0.f, c = 0.f;
    for (int i = threadIdx.x; i < n; i += 1024) {
        l += rowloss[i];
        c += rowcnt[i];
    }
    sl[threadIdx.x] = l;
    sc[threadIdx.x] = c;
    __syncthreads();
    for (int s = 512; s > 0; s >>= 1) {
        if (threadIdx.x < s) {
            sl[threadIdx.x] += sl[threadIdx.x + s];
            sc[threadIdx.x] += sc[threadIdx.x + s];
        }
        __syncthreads();
    }
    if (threadIdx.x == 0)
        out[0] = (sc[0] > 0.f) ? sl[0] / sc[0] : 0.f;
}

extern "C" void kernel_launch(void* const* d_in, const int* in_sizes, int n_in,
                              void* d_out, int out_size, void* d_ws, size_t ws_size,
                              hipStream_t stream) {
    const float* emb     = (const float*)d_in[0];
    const int*   classes = (const int*)d_in[1];
    float*       out     = (float*)d_out;
    const int n  = in_sizes[1];               // 8192
    const int nb = n / BT;                    // 64
    const int npairs = nb * (nb + 1) / 2;     // 2080

    ushort* normed  = (ushort*)d_ws;                                   // 8 MB
    float*  Zpart   = (float*)((char*)d_ws + (size_t)n * D * 2);       // 6 MB
    float*  rowloss = Zpart + (size_t)3 * 64 * n;
    float*  rowcnt  = rowloss + n;
    int*    hist    = (int*)(rowcnt + n);                              // 4 KB

    k_hist<<<1, 1024, 0, stream>>>(classes, hist, n);
    k_normalize<<<n / 4, 256, 0, stream>>>(emb, normed, n);
    k_zgemm<<<npairs, 256, 0, stream>>>(normed, classes, Zpart, n, nb, npairs);
    k_rowterms<<<(n + 255) / 256, 256, 0, stream>>>(Zpart, classes, hist, rowloss, rowcnt, n);
    k_final<<<1, 1024, 0, stream>>>(rowloss, rowcnt, out, n);
}